// Round 6
// baseline (253.172 us; speedup 1.0000x reference)
//
#include <hip/hip_runtime.h>
#include <hip/hip_bf16.h>
#include <cstdint>
#include <cstddef>

typedef unsigned short u16;
typedef __attribute__((ext_vector_type(8))) __bf16 bf16x8;
typedef __attribute__((ext_vector_type(16))) float f32x16;

#define LPOS 4096
#define CDIM 256
// per-buffer LDS (u16): 8192 K (32 rows x 256c) + 5120 V (4 planes x 160 rows x 8j)
#define LDSBUF 13312

// async global->LDS 16B: LDS dst must be wave-uniform base + lane*16
#define GLOAD_LDS16(g, l)                                                      \
  __builtin_amdgcn_global_load_lds(                                            \
      (const __attribute__((address_space(1))) void*)(g),                      \
      (__attribute__((address_space(3))) void*)(l), 16, 0, 0)

__device__ __forceinline__ unsigned f2bfbits(float x) {
  union { float f; unsigned u; } v; v.f = x;
  return (v.u + 0x7FFFu + ((v.u >> 16) & 1u)) >> 16;
}
__device__ __forceinline__ unsigned packbf(float a, float b) {
  __hip_bfloat162 h2 = __float22bfloat162_rn(make_float2(a, b));
  return *(unsigned*)&h2;
}

// ------- fused normalize: stats + normalize + transpose + bf16 cast --------
__global__ void norm_fused(const float* __restrict__ t_in,
                           const float* __restrict__ s_in,
                           const float* __restrict__ r_in,
                           u16* __restrict__ qn, u16* __restrict__ ksn,
                           u16* __restrict__ krn) {
  __shared__ float tile[256 * 33];
  __shared__ float sums[256], sqs[256];
  __shared__ float mv[32], ivv[32];
  int idx = blockIdx.x;
  int ab = idx >> 7, lt = idx & 127;
  int arr = ab >> 1, b = ab & 1;
  int l0 = lt * 32;
  const float* inp = (arr == 0 ? t_in : arr == 1 ? s_in : r_in) + (size_t)b * CDIM * LPOS;
  u16* outp = (arr == 0 ? qn : arr == 1 ? ksn : krn) + (size_t)b * LPOS * CDIM;
  int t = threadIdx.x;
  int cg = t >> 5, l = t & 31;
  float sum = 0.f, sq = 0.f;
#pragma unroll 8
  for (int cc = 0; cc < 32; ++cc) {
    int c = cg * 32 + cc;
    float v = inp[(size_t)c * LPOS + l0 + l];
    tile[c * 33 + l] = v;
    sum += v; sq += v * v;
  }
  sums[t] = sum; sqs[t] = sq;
  __syncthreads();
  if (t < 32) {
    float s = 0.f, q = 0.f;
#pragma unroll
    for (int g = 0; g < 8; ++g) { s += sums[g * 32 + t]; q += sqs[g * 32 + t]; }
    float mean = s * (1.0f / CDIM);
    float nsq = q - s * s * (1.0f / CDIM);
    mv[t] = mean;
    ivv[t] = rsqrtf(fmaxf(nsq, 1e-20f));
  }
  __syncthreads();
  int c2 = t & 127, ph = t >> 7;
#pragma unroll 4
  for (int rr = 0; rr < 16; ++rr) {
    int pos = ph + rr * 2;
    float m = mv[pos], iv = ivv[pos];
    float v0 = (tile[(2 * c2) * 33 + pos] - m) * iv;
    float v1 = (tile[(2 * c2 + 1) * 33 + pos] - m) * iv;
    *(unsigned*)&outp[(size_t)(l0 + pos) * CDIM + 2 * c2] = packbf(v0, v1);
  }
}

// ---------------- build combined V tensors (bf16, [C_v][L]) -----------------
// vs: [2][32][4096]   ch: 0..3 src_feats, 4 ones, 5..31 zero
// vr: [2][160][4096]  ch: 0..150 sem, 151..154 ref_feats, 155 ones, 156..159 zero
__global__ void build_v(const float* __restrict__ sf, const float* __restrict__ rf,
                        const float* __restrict__ sem,
                        u16* __restrict__ vs, u16* __restrict__ vr) {
  int t = blockIdx.x * 256 + threadIdx.x;
  const int NVS = 2 * 32 * 4096;
  if (t < NVS) {
    int b = t >> 17;
    int c = (t >> 12) & 31;
    int j = t & 4095;
    float v = (c < 4) ? sf[((size_t)b * 4 + c) * LPOS + j] : (c == 4 ? 1.0f : 0.0f);
    vs[t] = (u16)f2bfbits(v);
  } else {
    int t2 = t - NVS;
    if (t2 < 2 * 160 * 4096) {
      int b = t2 / (160 * 4096);
      int rr = t2 % (160 * 4096);
      int c = rr >> 12, j = rr & 4095;
      float v = (c < 151) ? sem[((size_t)b * 151 + c) * LPOS + j]
              : (c < 155) ? rf[((size_t)b * 4 + (c - 151)) * LPOS + j]
              : (c == 155) ? 1.0f : 0.0f;
      vr[((size_t)b * 160 + c) * LPOS + j] = (u16)f2bfbits(v);
    }
  }
}

// ---------------- fused flash soft-warp ----------------
// S^T orientation: D[m=j][n=i] = sum_c K[j][c] * Q[i][c]
// PV: D[m=c][n=i]  = sum_j V[c][j] * P[j][i]
// R6 fix: the P-frag exchange previously used per-lane DYNAMIC indices into
// the S register vector (S[kbase+i], kbase divergent in h) -> backend expands
// divergent register indexing into huge select/waterfall code = the 60%
// VALUBusy plateau of R1-R5. Now: pack with STATIC indices, select packed
// u32s with plain cndmask ternaries. Bitwise-identical result.
template <int CT>
__device__ __forceinline__ void flash_body(
    const u16* __restrict__ qb, const u16* __restrict__ kb,
    const u16* __restrict__ vb, float* __restrict__ dst,
    u16 (*lds)[LDSBUF], int wave, int lane, int i_wave, int j_base, int iters) {
  int h = lane >> 5, ln = lane & 31;

  // Q fragments: B[k=c][n=i], lane n=ln, k = kt*16 + h*8 + t
  bf16x8 qf[16];
  const u16* qrow = qb + (size_t)(i_wave + ln) * CDIM;
#pragma unroll
  for (int kt = 0; kt < 16; ++kt)
    qf[kt] = *(const bf16x8*)(qrow + kt * 16 + h * 8);

  f32x16 O[CT];
#pragma unroll
  for (int c = 0; c < CT; ++c)
#pragma unroll
    for (int t = 0; t < 16; ++t) O[c][t] = 0.0f;

  // Producer: K 32 rows (XOR-swizzled 16B chunks); ref also V as 10 x 64-row
  // slots over flat [plane(4)][row(160)][8j] (slots may cross plane bounds:
  // per-lane global addr, contiguous LDS = exactly global_load_lds' contract).
  auto stage = [&](int j0s, int buf) {
#pragma unroll
    for (int g = 0; g < 4; ++g) {
      int G = wave * 4 + g;
      int j = 2 * G + h;
      GLOAD_LDS16(kb + (size_t)(j0s + j) * CDIM + (ln ^ (j & 7)) * 8,
                  &lds[buf][G * 512]);
    }
    if constexpr (CT == 5) {
#pragma unroll
      for (int g = 0; g < 3; ++g) {
        int s = wave * 3 + g;               // 0..11, use 0..9
        if (s < 10) {
          int f = s * 64 + lane;            // flat 16B-chunk index 0..639
          int p = f / 160;                  // plane = j-octet
          int c = f - p * 160;              // V channel row
          GLOAD_LDS16(vb + (size_t)c * LPOS + j0s + p * 8,
                      &lds[buf][8192 + s * 512]);
        }
      }
    }
  };

  // K ds_read swizzle (validated R4/R5)
  int kread_base = ln * 256 + 8 * (h ^ (ln & 1));
  int q = (ln >> 1) & 3;

  stage(j_base, 0);

  for (int jt = 0; jt < iters; ++jt) {
    int cur = jt & 1;
    int j0 = j_base + jt * 32;
    __syncthreads();            // drains prefetch(jt) — in flight a full iter

    // src: consumer V loads FIRST (before producer stage -> FIFO-safe)
    bf16x8 vf[2];
    if constexpr (CT == 1) {
#pragma unroll
      for (int kt2 = 0; kt2 < 2; ++kt2)
        vf[kt2] = *(const bf16x8*)(vb + (size_t)ln * LPOS + j0 + (2 * kt2 + h) * 8);
    }
    if (jt + 1 < iters) stage(j0 + 32, cur ^ 1);   // producer LAST
    const u16* lk = lds[cur];

    // QK: A = K (LDS, swizzled), B = Q (regs); 2-way split accumulator chain
    f32x16 Sa, Sb;
#pragma unroll
    for (int t = 0; t < 16; ++t) { Sa[t] = 0.0f; Sb[t] = 0.0f; }
#pragma unroll
    for (int kt = 0; kt < 16; kt += 2) {
      bf16x8 ka0 = *(const bf16x8*)&lk[kread_base + 16 * ((kt & 3) ^ q) + 64 * (kt >> 2)];
      Sa = __builtin_amdgcn_mfma_f32_32x32x16_bf16(ka0, qf[kt], Sa, 0, 0, 0);
      bf16x8 ka1 = *(const bf16x8*)&lk[kread_base + 16 * (((kt + 1) & 3) ^ q) + 64 * ((kt + 1) >> 2)];
      Sb = __builtin_amdgcn_mfma_f32_32x32x16_bf16(ka1, qf[kt + 1], Sb, 0, 0, 0);
    }
    // cosine sims in [-1,1]: exp directly, no max-subtract needed
    f32x16 S;
#pragma unroll
    for (int t = 0; t < 16; ++t) S[t] = __expf(Sa[t] + Sb[t]);

    // P^T C-layout -> PV B-frags. STATIC packs, then u32 selects + xor-32.
    bf16x8 pb[2];
#pragma unroll
    for (int kh = 0; kh < 2; ++kh) {
      unsigned c0 = packbf(S[kh * 8 + 0], S[kh * 8 + 1]);
      unsigned c1 = packbf(S[kh * 8 + 2], S[kh * 8 + 3]);
      unsigned c2 = packbf(S[kh * 8 + 4], S[kh * 8 + 5]);
      unsigned c3 = packbf(S[kh * 8 + 6], S[kh * 8 + 7]);
      unsigned keep0 = h ? c2 : c0, keep1 = h ? c3 : c1;
      unsigned send0 = h ? c0 : c2, send1 = h ? c1 : c3;
      unsigned recv0 = (unsigned)__shfl_xor((int)send0, 32, 64);
      unsigned recv1 = (unsigned)__shfl_xor((int)send1, 32, 64);
      union { unsigned u[4]; bf16x8 v; } tmp;
      tmp.u[0] = h ? recv0 : keep0;
      tmp.u[1] = h ? recv1 : keep1;
      tmp.u[2] = h ? keep0 : recv0;
      tmp.u[3] = h ? keep1 : recv1;
      pb[kh] = tmp.v;
    }

    // PV: A = V (ref: LDS planes; src: regs), B = P
#pragma unroll
    for (int ct = 0; ct < CT; ++ct)
#pragma unroll
      for (int kt2 = 0; kt2 < 2; ++kt2) {
        bf16x8 va;
        if constexpr (CT == 5)
          va = *(const bf16x8*)&lk[8192 + ((2 * kt2 + h) * 160 + ct * 32 + ln) * 8];
        else
          va = vf[kt2];
        O[ct] = __builtin_amdgcn_mfma_f32_32x32x16_bf16(va, pb[kt2], O[ct], 0, 0, 0);
      }
  }

  // epilogue: D rows = c, cols = i
#pragma unroll
  for (int ct = 0; ct < CT; ++ct)
#pragma unroll
    for (int t = 0; t < 16; ++t) {
      int c = ct * 32 + (t & 3) + 8 * (t >> 2) + 4 * h;
      dst[(size_t)c * LPOS + i_wave + ln] = O[ct][t];
    }
}

// 52 KB LDS -> 3 blocks/CU; (256,3) caps VGPR at 170 (allocator reloads Q
// from L2 rather than spilling — R5 evidence: fit 124 under looser cap).
// Grid: exact 1:2 ref:src interleave so each CU co-schedules mixed blocks.
__global__ __launch_bounds__(256, 3) void flash(
    const u16* __restrict__ qn, const u16* __restrict__ ksn, const u16* __restrict__ krn,
    const u16* __restrict__ vs, const u16* __restrict__ vr,
    float* __restrict__ nsrc, float* __restrict__ nref,
    int nch_src, int nch_ref) {
  __shared__ u16 lds[2][LDSBUF];   // 52 KB
  int tid = threadIdx.x;
  int wave = tid >> 6, lane = tid & 63;
  int idx = blockIdx.x;
  int third = idx / 3, m = idx - third * 3;
  if (m == 0) {                      // ref block
    int r = third;
    int chunk = r >> 6, b = (r >> 5) & 1, wgi = r & 31;
    int jchunk = LPOS / nch_ref;
    flash_body<5>(qn + (size_t)b * LPOS * CDIM, krn + (size_t)b * LPOS * CDIM,
                  vr + (size_t)b * 160 * LPOS,
                  nref + (size_t)(chunk * 2 + b) * 160 * LPOS,
                  lds, wave, lane, wgi * 128 + wave * 32, chunk * jchunk,
                  jchunk / 32);
  } else {                           // src block
    int r = idx - third - 1;
    int chunk = r >> 6, b = (r >> 5) & 1, wgi = r & 31;
    int jchunk = LPOS / nch_src;
    flash_body<1>(qn + (size_t)b * LPOS * CDIM, ksn + (size_t)b * LPOS * CDIM,
                  vs + (size_t)b * 32 * LPOS,
                  nsrc + (size_t)(chunk * 2 + b) * 32 * LPOS,
                  lds, wave, lane, wgi * 128 + wave * 32, chunk * jchunk,
                  jchunk / 32);
  }
}

// ---------------- finalize: sum chunks, divide by ones-channel --------------
__global__ void finalize(const float* __restrict__ nsrc, const float* __restrict__ nref,
                         float* __restrict__ out, int nch_src, int nch_ref) {
  int t = blockIdx.x * 256 + threadIdx.x;
  if (t >= 1302528) return;
  if (t < 32768) {                        // warped_src_feat [2][4][4096]
    int b = t >> 14, c = (t >> 12) & 3, i = t & 4095;
    float num = 0.f, den = 0.f;
    for (int k = 0; k < nch_src; ++k) {
      const float* base = nsrc + ((size_t)(k * 2 + b) * 32) * LPOS;
      num += base[(size_t)c * LPOS + i];
      den += base[(size_t)4 * LPOS + i];
    }
    out[t] = num / den;
  } else if (t < 65536) {                 // warped_ref_feat [2][4][4096]
    int t1 = t - 32768;
    int b = t1 >> 14, c = (t1 >> 12) & 3, i = t1 & 4095;
    float num = 0.f, den = 0.f;
    for (int k = 0; k < nch_ref; ++k) {
      const float* base = nref + ((size_t)(k * 2 + b) * 160) * LPOS;
      num += base[(size_t)(151 + c) * LPOS + i];
      den += base[(size_t)155 * LPOS + i];
    }
    out[t] = num / den;
  } else {                                // warped_ref_seg [2][151][4096]
    int t2 = t - 65536;
    int b = t2 / 618496;
    int rr = t2 % 618496;
    int c = rr >> 12, i = rr & 4095;
    float num = 0.f, den = 0.f;
    for (int k = 0; k < nch_ref; ++k) {
      const float* base = nref + ((size_t)(k * 2 + b) * 160) * LPOS;
      num += base[(size_t)c * LPOS + i];
      den += base[(size_t)155 * LPOS + i];
    }
    out[t] = num / den;
  }
}

extern "C" void kernel_launch(void* const* d_in, const int* in_sizes, int n_in,
                              void* d_out, int out_size, void* d_ws, size_t ws_size,
                              hipStream_t stream) {
  const float* trg  = (const float*)d_in[0];
  const float* srcp = (const float*)d_in[1];
  const float* refp = (const float*)d_in[2];
  const float* sfeat = (const float*)d_in[3];
  const float* rfeat = (const float*)d_in[4];
  const float* rsem  = (const float*)d_in[5];
  float* out = (float*)d_out;

  char* ws = (char*)d_ws;
  size_t o = 0;
  auto alloc = [&](size_t bytes) -> char* {
    char* p = ws + o;
    o += (bytes + 255) & ~(size_t)255;
    return p;
  };
  u16* qn  = (u16*)alloc(2ull * LPOS * CDIM * 2);
  u16* ksn = (u16*)alloc(2ull * LPOS * CDIM * 2);
  u16* krn = (u16*)alloc(2ull * LPOS * CDIM * 2);
  u16* vs  = (u16*)alloc(2ull * 32 * LPOS * 2);
  u16* vr  = (u16*)alloc(2ull * 160 * LPOS * 2);

  size_t fixed = o;
  int nch_ref = 8;                       // nch_src = 2*nch_ref (keeps 1:2 grid)
  for (;;) {
    size_t need = fixed + 512 +
                  (size_t)(2 * nch_ref) * 2 * 32 * LPOS * 4 +
                  (size_t)nch_ref * 2 * 160 * LPOS * 4;
    if (need <= ws_size || nch_ref == 1) break;
    nch_ref >>= 1;
  }
  int nch_src = 2 * nch_ref;
  float* nsrc = (float*)alloc((size_t)nch_src * 2 * 32 * LPOS * 4);
  float* nref = (float*)alloc((size_t)nch_ref * 2 * 160 * LPOS * 4);

  hipLaunchKernelGGL(norm_fused, dim3(768), dim3(256), 0, stream,
                     trg, srcp, refp, qn, ksn, krn);
  hipLaunchKernelGGL(build_v, dim3(6144), dim3(256), 0, stream,
                     sfeat, rfeat, rsem, vs, vr);
  hipLaunchKernelGGL(flash, dim3(64 * nch_ref * 3), dim3(256), 0, stream,
                     qn, ksn, krn, vs, vr, nsrc, nref, nch_src, nch_ref);
  hipLaunchKernelGGL(finalize, dim3(5088), dim3(256), 0, stream,
                     nsrc, nref, out, nch_src, nch_ref);
}

// Round 7
// 169.190 us; speedup vs baseline: 1.4964x; 1.4964x over previous
//
#include <hip/hip_runtime.h>
#include <hip/hip_bf16.h>
#include <cstdint>
#include <cstddef>

typedef unsigned short u16;
typedef __attribute__((ext_vector_type(8))) __bf16 bf16x8;
typedef __attribute__((ext_vector_type(16))) float f32x16;

#define LPOS 4096
#define CDIM 256
// per-buffer LDS (u16): 8192 K (32 rows x 256c) + 5120 V (4 planes x 160 rows x 8j)
#define LDSBUF 13312

// async global->LDS 16B: LDS dst must be wave-uniform base + lane*16
#define GLOAD_LDS16(g, l)                                                      \
  __builtin_amdgcn_global_load_lds(                                            \
      (const __attribute__((address_space(1))) void*)(g),                      \
      (__attribute__((address_space(3))) void*)(l), 16, 0, 0)

__device__ __forceinline__ unsigned f2bfbits(float x) {
  union { float f; unsigned u; } v; v.f = x;
  return (v.u + 0x7FFFu + ((v.u >> 16) & 1u)) >> 16;
}
__device__ __forceinline__ unsigned packbf(float a, float b) {
  __hip_bfloat162 h2 = __float22bfloat162_rn(make_float2(a, b));
  return *(unsigned*)&h2;
}

// ------- fused normalize: stats + normalize + transpose + bf16 cast --------
__global__ void norm_fused(const float* __restrict__ t_in,
                           const float* __restrict__ s_in,
                           const float* __restrict__ r_in,
                           u16* __restrict__ qn, u16* __restrict__ ksn,
                           u16* __restrict__ krn) {
  __shared__ float tile[256 * 33];
  __shared__ float sums[256], sqs[256];
  __shared__ float mv[32], ivv[32];
  int idx = blockIdx.x;
  int ab = idx >> 7, lt = idx & 127;
  int arr = ab >> 1, b = ab & 1;
  int l0 = lt * 32;
  const float* inp = (arr == 0 ? t_in : arr == 1 ? s_in : r_in) + (size_t)b * CDIM * LPOS;
  u16* outp = (arr == 0 ? qn : arr == 1 ? ksn : krn) + (size_t)b * LPOS * CDIM;
  int t = threadIdx.x;
  int cg = t >> 5, l = t & 31;
  float sum = 0.f, sq = 0.f;
#pragma unroll 8
  for (int cc = 0; cc < 32; ++cc) {
    int c = cg * 32 + cc;
    float v = inp[(size_t)c * LPOS + l0 + l];
    tile[c * 33 + l] = v;
    sum += v; sq += v * v;
  }
  sums[t] = sum; sqs[t] = sq;
  __syncthreads();
  if (t < 32) {
    float s = 0.f, q = 0.f;
#pragma unroll
    for (int g = 0; g < 8; ++g) { s += sums[g * 32 + t]; q += sqs[g * 32 + t]; }
    float mean = s * (1.0f / CDIM);
    float nsq = q - s * s * (1.0f / CDIM);
    mv[t] = mean;
    ivv[t] = rsqrtf(fmaxf(nsq, 1e-20f));
  }
  __syncthreads();
  int c2 = t & 127, ph = t >> 7;
#pragma unroll 4
  for (int rr = 0; rr < 16; ++rr) {
    int pos = ph + rr * 2;
    float m = mv[pos], iv = ivv[pos];
    float v0 = (tile[(2 * c2) * 33 + pos] - m) * iv;
    float v1 = (tile[(2 * c2 + 1) * 33 + pos] - m) * iv;
    *(unsigned*)&outp[(size_t)(l0 + pos) * CDIM + 2 * c2] = packbf(v0, v1);
  }
}

// ---------------- build combined V tensors (bf16, [C_v][L]) -----------------
// vs: [2][32][4096]   ch: 0..3 src_feats, 4 ones, 5..31 zero
// vr: [2][160][4096]  ch: 0..150 sem, 151..154 ref_feats, 155 ones, 156..159 zero
__global__ void build_v(const float* __restrict__ sf, const float* __restrict__ rf,
                        const float* __restrict__ sem,
                        u16* __restrict__ vs, u16* __restrict__ vr) {
  int t = blockIdx.x * 256 + threadIdx.x;
  const int NVS = 2 * 32 * 4096;
  if (t < NVS) {
    int b = t >> 17;
    int c = (t >> 12) & 31;
    int j = t & 4095;
    float v = (c < 4) ? sf[((size_t)b * 4 + c) * LPOS + j] : (c == 4 ? 1.0f : 0.0f);
    vs[t] = (u16)f2bfbits(v);
  } else {
    int t2 = t - NVS;
    if (t2 < 2 * 160 * 4096) {
      int b = t2 / (160 * 4096);
      int rr = t2 % (160 * 4096);
      int c = rr >> 12, j = rr & 4095;
      float v = (c < 151) ? sem[((size_t)b * 151 + c) * LPOS + j]
              : (c < 155) ? rf[((size_t)b * 4 + (c - 151)) * LPOS + j]
              : (c == 155) ? 1.0f : 0.0f;
      vr[((size_t)b * 160 + c) * LPOS + j] = (u16)f2bfbits(v);
    }
  }
}

// ---------------- fused flash soft-warp ----------------
// S^T orientation: D[m=j][n=i] = sum_c K[j][c] * Q[i][c]
// PV: D[m=c][n=i]  = sum_j V[c][j] * P[j][i]
// R6 fix (kept): P-frag exchange uses STATIC register indices + u32 cndmask
// selects (divergent dynamic S[kbase+i] extraction waterfalled -> 60% VALU).
// R7 fix: back to (256,2). (256,3)'s 170-reg cap spilled qf/O to scratch
// (VGPR 84, FETCH 217 MB, 167 us). This kernel needs the full 256-reg budget.
template <int CT>
__device__ __forceinline__ void flash_body(
    const u16* __restrict__ qb, const u16* __restrict__ kb,
    const u16* __restrict__ vb, float* __restrict__ dst,
    u16 (*lds)[LDSBUF], int wave, int lane, int i_wave, int j_base, int iters) {
  int h = lane >> 5, ln = lane & 31;

  // Q fragments: B[k=c][n=i], lane n=ln, k = kt*16 + h*8 + t
  bf16x8 qf[16];
  const u16* qrow = qb + (size_t)(i_wave + ln) * CDIM;
#pragma unroll
  for (int kt = 0; kt < 16; ++kt)
    qf[kt] = *(const bf16x8*)(qrow + kt * 16 + h * 8);

  f32x16 O[CT];
#pragma unroll
  for (int c = 0; c < CT; ++c)
#pragma unroll
    for (int t = 0; t < 16; ++t) O[c][t] = 0.0f;

  // Producer: K 32 rows (XOR-swizzled 16B chunks); ref also V as 10 x 64-row
  // slots over flat [plane(4)][row(160)][8j] (slots may cross plane bounds:
  // per-lane global addr, contiguous LDS = exactly global_load_lds' contract).
  auto stage = [&](int j0s, int buf) {
#pragma unroll
    for (int g = 0; g < 4; ++g) {
      int G = wave * 4 + g;
      int j = 2 * G + h;
      GLOAD_LDS16(kb + (size_t)(j0s + j) * CDIM + (ln ^ (j & 7)) * 8,
                  &lds[buf][G * 512]);
    }
    if constexpr (CT == 5) {
#pragma unroll
      for (int g = 0; g < 3; ++g) {
        int s = wave * 3 + g;               // 0..11, use 0..9
        if (s < 10) {
          int f = s * 64 + lane;            // flat 16B-chunk index 0..639
          int p = f / 160;                  // plane = j-octet
          int c = f - p * 160;              // V channel row
          GLOAD_LDS16(vb + (size_t)c * LPOS + j0s + p * 8,
                      &lds[buf][8192 + s * 512]);
        }
      }
    }
  };

  // K ds_read swizzle (validated R4/R5)
  int kread_base = ln * 256 + 8 * (h ^ (ln & 1));
  int q = (ln >> 1) & 3;

  stage(j_base, 0);

  for (int jt = 0; jt < iters; ++jt) {
    int cur = jt & 1;
    int j0 = j_base + jt * 32;
    __syncthreads();            // drains prefetch(jt) — in flight a full iter

    // src: consumer V loads FIRST (before producer stage -> FIFO-safe)
    bf16x8 vf[2];
    if constexpr (CT == 1) {
#pragma unroll
      for (int kt2 = 0; kt2 < 2; ++kt2)
        vf[kt2] = *(const bf16x8*)(vb + (size_t)ln * LPOS + j0 + (2 * kt2 + h) * 8);
    }
    if (jt + 1 < iters) stage(j0 + 32, cur ^ 1);   // producer LAST
    const u16* lk = lds[cur];

    // QK: A = K (LDS, swizzled), B = Q (regs); 2-way split accumulator chain
    f32x16 Sa, Sb;
#pragma unroll
    for (int t = 0; t < 16; ++t) { Sa[t] = 0.0f; Sb[t] = 0.0f; }
#pragma unroll
    for (int kt = 0; kt < 16; kt += 2) {
      bf16x8 ka0 = *(const bf16x8*)&lk[kread_base + 16 * ((kt & 3) ^ q) + 64 * (kt >> 2)];
      Sa = __builtin_amdgcn_mfma_f32_32x32x16_bf16(ka0, qf[kt], Sa, 0, 0, 0);
      bf16x8 ka1 = *(const bf16x8*)&lk[kread_base + 16 * (((kt + 1) & 3) ^ q) + 64 * ((kt + 1) >> 2)];
      Sb = __builtin_amdgcn_mfma_f32_32x32x16_bf16(ka1, qf[kt + 1], Sb, 0, 0, 0);
    }
    // cosine sims in [-1,1]: exp directly, no max-subtract needed
    f32x16 S;
#pragma unroll
    for (int t = 0; t < 16; ++t) S[t] = __expf(Sa[t] + Sb[t]);

    // P^T C-layout -> PV B-frags. STATIC packs, then u32 selects + xor-32.
    bf16x8 pb[2];
#pragma unroll
    for (int kh = 0; kh < 2; ++kh) {
      unsigned c0 = packbf(S[kh * 8 + 0], S[kh * 8 + 1]);
      unsigned c1 = packbf(S[kh * 8 + 2], S[kh * 8 + 3]);
      unsigned c2 = packbf(S[kh * 8 + 4], S[kh * 8 + 5]);
      unsigned c3 = packbf(S[kh * 8 + 6], S[kh * 8 + 7]);
      unsigned keep0 = h ? c2 : c0, keep1 = h ? c3 : c1;
      unsigned send0 = h ? c0 : c2, send1 = h ? c1 : c3;
      unsigned recv0 = (unsigned)__shfl_xor((int)send0, 32, 64);
      unsigned recv1 = (unsigned)__shfl_xor((int)send1, 32, 64);
      union { unsigned u[4]; bf16x8 v; } tmp;
      tmp.u[0] = h ? recv0 : keep0;
      tmp.u[1] = h ? recv1 : keep1;
      tmp.u[2] = h ? keep0 : recv0;
      tmp.u[3] = h ? keep1 : recv1;
      pb[kh] = tmp.v;
    }

    // PV: A = V (ref: LDS planes; src: regs), B = P
#pragma unroll
    for (int ct = 0; ct < CT; ++ct)
#pragma unroll
      for (int kt2 = 0; kt2 < 2; ++kt2) {
        bf16x8 va;
        if constexpr (CT == 5)
          va = *(const bf16x8*)&lk[8192 + ((2 * kt2 + h) * 160 + ct * 32 + ln) * 8];
        else
          va = vf[kt2];
        O[ct] = __builtin_amdgcn_mfma_f32_32x32x16_bf16(va, pb[kt2], O[ct], 0, 0, 0);
      }
  }

  // epilogue: D rows = c, cols = i
#pragma unroll
  for (int ct = 0; ct < CT; ++ct)
#pragma unroll
    for (int t = 0; t < 16; ++t) {
      int c = ct * 32 + (t & 3) + 8 * (t >> 2) + 4 * h;
      dst[(size_t)c * LPOS + i_wave + ln] = O[ct][t];
    }
}

// 52 KB LDS, (256,2): full 256-reg budget (no spill — R5 proof), 2 blocks/CU.
// Grid: exact 1:2 ref:src interleave so each CU co-schedules mixed blocks.
__global__ __launch_bounds__(256, 2) void flash(
    const u16* __restrict__ qn, const u16* __restrict__ ksn, const u16* __restrict__ krn,
    const u16* __restrict__ vs, const u16* __restrict__ vr,
    float* __restrict__ nsrc, float* __restrict__ nref,
    int nch_src, int nch_ref) {
  __shared__ u16 lds[2][LDSBUF];   // 52 KB
  int tid = threadIdx.x;
  int wave = tid >> 6, lane = tid & 63;
  int idx = blockIdx.x;
  int third = idx / 3, m = idx - third * 3;
  if (m == 0) {                      // ref block
    int r = third;
    int chunk = r >> 6, b = (r >> 5) & 1, wgi = r & 31;
    int jchunk = LPOS / nch_ref;
    flash_body<5>(qn + (size_t)b * LPOS * CDIM, krn + (size_t)b * LPOS * CDIM,
                  vr + (size_t)b * 160 * LPOS,
                  nref + (size_t)(chunk * 2 + b) * 160 * LPOS,
                  lds, wave, lane, wgi * 128 + wave * 32, chunk * jchunk,
                  jchunk / 32);
  } else {                           // src block
    int r = idx - third - 1;
    int chunk = r >> 6, b = (r >> 5) & 1, wgi = r & 31;
    int jchunk = LPOS / nch_src;
    flash_body<1>(qn + (size_t)b * LPOS * CDIM, ksn + (size_t)b * LPOS * CDIM,
                  vs + (size_t)b * 32 * LPOS,
                  nsrc + (size_t)(chunk * 2 + b) * 32 * LPOS,
                  lds, wave, lane, wgi * 128 + wave * 32, chunk * jchunk,
                  jchunk / 32);
  }
}

// ---------------- finalize: sum chunks, divide by ones-channel --------------
__global__ void finalize(const float* __restrict__ nsrc, const float* __restrict__ nref,
                         float* __restrict__ out, int nch_src, int nch_ref) {
  int t = blockIdx.x * 256 + threadIdx.x;
  if (t >= 1302528) return;
  if (t < 32768) {                        // warped_src_feat [2][4][4096]
    int b = t >> 14, c = (t >> 12) & 3, i = t & 4095;
    float num = 0.f, den = 0.f;
    for (int k = 0; k < nch_src; ++k) {
      const float* base = nsrc + ((size_t)(k * 2 + b) * 32) * LPOS;
      num += base[(size_t)c * LPOS + i];
      den += base[(size_t)4 * LPOS + i];
    }
    out[t] = num / den;
  } else if (t < 65536) {                 // warped_ref_feat [2][4][4096]
    int t1 = t - 32768;
    int b = t1 >> 14, c = (t1 >> 12) & 3, i = t1 & 4095;
    float num = 0.f, den = 0.f;
    for (int k = 0; k < nch_ref; ++k) {
      const float* base = nref + ((size_t)(k * 2 + b) * 160) * LPOS;
      num += base[(size_t)(151 + c) * LPOS + i];
      den += base[(size_t)155 * LPOS + i];
    }
    out[t] = num / den;
  } else {                                // warped_ref_seg [2][151][4096]
    int t2 = t - 65536;
    int b = t2 / 618496;
    int rr = t2 % 618496;
    int c = rr >> 12, i = rr & 4095;
    float num = 0.f, den = 0.f;
    for (int k = 0; k < nch_ref; ++k) {
      const float* base = nref + ((size_t)(k * 2 + b) * 160) * LPOS;
      num += base[(size_t)c * LPOS + i];
      den += base[(size_t)155 * LPOS + i];
    }
    out[t] = num / den;
  }
}

extern "C" void kernel_launch(void* const* d_in, const int* in_sizes, int n_in,
                              void* d_out, int out_size, void* d_ws, size_t ws_size,
                              hipStream_t stream) {
  const float* trg  = (const float*)d_in[0];
  const float* srcp = (const float*)d_in[1];
  const float* refp = (const float*)d_in[2];
  const float* sfeat = (const float*)d_in[3];
  const float* rfeat = (const float*)d_in[4];
  const float* rsem  = (const float*)d_in[5];
  float* out = (float*)d_out;

  char* ws = (char*)d_ws;
  size_t o = 0;
  auto alloc = [&](size_t bytes) -> char* {
    char* p = ws + o;
    o += (bytes + 255) & ~(size_t)255;
    return p;
  };
  u16* qn  = (u16*)alloc(2ull * LPOS * CDIM * 2);
  u16* ksn = (u16*)alloc(2ull * LPOS * CDIM * 2);
  u16* krn = (u16*)alloc(2ull * LPOS * CDIM * 2);
  u16* vs  = (u16*)alloc(2ull * 32 * LPOS * 2);
  u16* vr  = (u16*)alloc(2ull * 160 * LPOS * 2);

  size_t fixed = o;
  int nch_ref = 8;                       // nch_src = 2*nch_ref (keeps 1:2 grid)
  for (;;) {
    size_t need = fixed + 512 +
                  (size_t)(2 * nch_ref) * 2 * 32 * LPOS * 4 +
                  (size_t)nch_ref * 2 * 160 * LPOS * 4;
    if (need <= ws_size || nch_ref == 1) break;
    nch_ref >>= 1;
  }
  int nch_src = 2 * nch_ref;
  float* nsrc = (float*)alloc((size_t)nch_src * 2 * 32 * LPOS * 4);
  float* nref = (float*)alloc((size_t)nch_ref * 2 * 160 * LPOS * 4);

  hipLaunchKernelGGL(norm_fused, dim3(768), dim3(256), 0, stream,
                     trg, srcp, refp, qn, ksn, krn);
  hipLaunchKernelGGL(build_v, dim3(6144), dim3(256), 0, stream,
                     sfeat, rfeat, rsem, vs, vr);
  hipLaunchKernelGGL(flash, dim3(64 * nch_ref * 3), dim3(256), 0, stream,
                     qn, ksn, krn, vs, vr, nsrc, nref, nch_src, nch_ref);
  hipLaunchKernelGGL(finalize, dim3(5088), dim3(256), 0, stream,
                     nsrc, nref, out, nch_src, nch_ref);
}

// Round 8
// 168.544 us; speedup vs baseline: 1.5021x; 1.0038x over previous
//
#include <hip/hip_runtime.h>
#include <hip/hip_bf16.h>
#include <cstdint>
#include <cstddef>

typedef unsigned short u16;
typedef __attribute__((ext_vector_type(8))) __bf16 bf16x8;
typedef __attribute__((ext_vector_type(4))) unsigned u32x4;
typedef __attribute__((ext_vector_type(16))) float f32x16;

#define LPOS 4096
#define CDIM 256
// per-buffer LDS (u16): 8192 K (32 rows x 256c) + 5120 V (4 planes x 160 rows x 8j)
#define LDSBUF 13312

#if __has_builtin(__builtin_amdgcn_exp2f)
#define EXP2(x) __builtin_amdgcn_exp2f(x)
#else
#define EXP2(x) exp2f(x)
#endif

// async global->LDS 16B: LDS dst must be wave-uniform base + lane*16
#define GLOAD_LDS16(g, l)                                                      \
  __builtin_amdgcn_global_load_lds(                                            \
      (const __attribute__((address_space(1))) void*)(g),                      \
      (__attribute__((address_space(3))) void*)(l), 16, 0, 0)

__device__ __forceinline__ unsigned f2bfbits(float x) {
  union { float f; unsigned u; } v; v.f = x;
  return (v.u + 0x7FFFu + ((v.u >> 16) & 1u)) >> 16;
}
__device__ __forceinline__ unsigned packbf(float a, float b) {
  __hip_bfloat162 h2 = __float22bfloat162_rn(make_float2(a, b));
  return *(unsigned*)&h2;
}

// ------- fused normalize: stats + normalize + transpose + bf16 cast --------
// Q (arr==0) is pre-scaled by log2(e): downstream uses exp2(Q.K) == exp(q.k).
__global__ void norm_fused(const float* __restrict__ t_in,
                           const float* __restrict__ s_in,
                           const float* __restrict__ r_in,
                           u16* __restrict__ qn, u16* __restrict__ ksn,
                           u16* __restrict__ krn) {
  __shared__ float tile[256 * 33];
  __shared__ float sums[256], sqs[256];
  __shared__ float mv[32], ivv[32];
  int idx = blockIdx.x;
  int ab = idx >> 7, lt = idx & 127;
  int arr = ab >> 1, b = ab & 1;
  int l0 = lt * 32;
  const float* inp = (arr == 0 ? t_in : arr == 1 ? s_in : r_in) + (size_t)b * CDIM * LPOS;
  u16* outp = (arr == 0 ? qn : arr == 1 ? ksn : krn) + (size_t)b * LPOS * CDIM;
  float scale = (arr == 0) ? 1.4426950408889634f : 1.0f;
  int t = threadIdx.x;
  int cg = t >> 5, l = t & 31;
  float sum = 0.f, sq = 0.f;
#pragma unroll 8
  for (int cc = 0; cc < 32; ++cc) {
    int c = cg * 32 + cc;
    float v = inp[(size_t)c * LPOS + l0 + l];
    tile[c * 33 + l] = v;
    sum += v; sq += v * v;
  }
  sums[t] = sum; sqs[t] = sq;
  __syncthreads();
  if (t < 32) {
    float s = 0.f, q = 0.f;
#pragma unroll
    for (int g = 0; g < 8; ++g) { s += sums[g * 32 + t]; q += sqs[g * 32 + t]; }
    float mean = s * (1.0f / CDIM);
    float nsq = q - s * s * (1.0f / CDIM);
    mv[t] = mean;
    ivv[t] = rsqrtf(fmaxf(nsq, 1e-20f)) * scale;
  }
  __syncthreads();
  int c2 = t & 127, ph = t >> 7;
#pragma unroll 4
  for (int rr = 0; rr < 16; ++rr) {
    int pos = ph + rr * 2;
    float m = mv[pos], iv = ivv[pos];
    float v0 = (tile[(2 * c2) * 33 + pos] - m) * iv;
    float v1 = (tile[(2 * c2 + 1) * 33 + pos] - m) * iv;
    *(unsigned*)&outp[(size_t)(l0 + pos) * CDIM + 2 * c2] = packbf(v0, v1);
  }
}

// ---------------- build combined V tensors (bf16, [C_v][L]) -----------------
// vs: [2][32][4096]   ch: 0..3 src_feats, 4 ones, 5..31 zero
// vr: [2][160][4096]  ch: 0..150 sem, 151..154 ref_feats, 155 ones, 156..159 zero
__global__ void build_v(const float* __restrict__ sf, const float* __restrict__ rf,
                        const float* __restrict__ sem,
                        u16* __restrict__ vs, u16* __restrict__ vr) {
  int t = blockIdx.x * 256 + threadIdx.x;
  const int NVS = 2 * 32 * 4096;
  if (t < NVS) {
    int b = t >> 17;
    int c = (t >> 12) & 31;
    int j = t & 4095;
    float v = (c < 4) ? sf[((size_t)b * 4 + c) * LPOS + j] : (c == 4 ? 1.0f : 0.0f);
    vs[t] = (u16)f2bfbits(v);
  } else {
    int t2 = t - NVS;
    if (t2 < 2 * 160 * 4096) {
      int b = t2 / (160 * 4096);
      int rr = t2 % (160 * 4096);
      int c = rr >> 12, j = rr & 4095;
      float v = (c < 151) ? sem[((size_t)b * 151 + c) * LPOS + j]
              : (c < 155) ? rf[((size_t)b * 4 + (c - 151)) * LPOS + j]
              : (c == 155) ? 1.0f : 0.0f;
      vr[((size_t)b * 160 + c) * LPOS + j] = (u16)f2bfbits(v);
    }
  }
}

// ---------------- fused flash soft-warp ----------------
// S^T orientation: D[m=j][n=i] = sum_c K[j][c] * Q[i][c]
// PV: D[m=c][n=i]  = sum_j V[c][j] * P[j][i]
// R8 fixes:
//  (a) qf PINNED via opaque asm — R7's VGPR=120 proved the allocator was
//      rematerializing Q fragments as per-iteration GLOBAL reloads, whose
//      FIFO waits drained the K-prefetch mid-iteration (the hidden stall).
//  (b) jt-loop manually unrolled x2 so buf is a literal: all LDS reads are
//      precomputed base pointers + immediate offsets (no per-iter addr VALU).
//  (c) exp2 path: Q pre-scaled by log2e -> single v_exp_f32 per element.
template <int CT>
__device__ __forceinline__ void flash_body(
    const u16* __restrict__ qb, const u16* __restrict__ kb,
    const u16* __restrict__ vb, float* __restrict__ dst,
    u16 (*lds)[LDSBUF], int wave, int lane, int i_wave, int j_base, int iters) {
  int h = lane >> 5, ln = lane & 31;

  // Q fragments: B[k=c][n=i], lane n=ln, k = kt*16 + h*8 + t
  bf16x8 qf[16];
  const u16* qrow = qb + (size_t)(i_wave + ln) * CDIM;
#pragma unroll
  for (int kt = 0; kt < 16; ++kt)
    qf[kt] = *(const bf16x8*)(qrow + kt * 16 + h * 8);
  // pin: asm results cannot be rematerialized -> qf stays in VGPRs
#pragma unroll
  for (int kt = 0; kt < 16; ++kt)
    asm volatile("" : "+v"(*(u32x4*)&qf[kt]));

  f32x16 O[CT];
#pragma unroll
  for (int c = 0; c < CT; ++c)
#pragma unroll
    for (int t = 0; t < 16; ++t) O[c][t] = 0.0f;

  // Producer: K 32 rows (XOR-swizzled 16B chunks); ref also V as 10 x 64-row
  // slots over flat [plane(4)][row(160)][8j].
  auto stage = [&](int j0s, int buf) {
#pragma unroll
    for (int g = 0; g < 4; ++g) {
      int G = wave * 4 + g;
      int j = 2 * G + h;
      GLOAD_LDS16(kb + (size_t)(j0s + j) * CDIM + (ln ^ (j & 7)) * 8,
                  &lds[buf][G * 512]);
    }
    if constexpr (CT == 5) {
#pragma unroll
      for (int g = 0; g < 3; ++g) {
        int s = wave * 3 + g;               // 0..11, use 0..9
        if (s < 10) {
          int f = s * 64 + lane;            // flat 16B-chunk index 0..639
          int p = f / 160;                  // plane = j-octet
          int c = f - p * 160;              // V channel row
          GLOAD_LDS16(vb + (size_t)c * LPOS + j0s + p * 8,
                      &lds[buf][8192 + s * 512]);
        }
      }
    }
  };

  // Precomputed LDS read bases (buf 0); buf 1 = +LDSBUF via immediate.
  // K addr(kt,buf) = ka[kt&3] + 64*(kt>>2) + buf*LDSBUF   (u16 units)
  int kread_base = ln * 256 + 8 * (h ^ (ln & 1));
  int q = (ln >> 1) & 3;
  const u16* ka[4];
#pragma unroll
  for (int m = 0; m < 4; ++m) ka[m] = &lds[0][kread_base + 16 * (m ^ q)];
  // V(ref) addr(kt2,ct,buf) = va + kt2*2560 + ct*256 + buf*LDSBUF
  const u16* va = &lds[0][8192 + h * 1280 + ln * 8];

  auto iter_body = [&](int jt, int buf) {
    int j0 = j_base + jt * 32;
    int bo = buf * LDSBUF;      // literal after unroll -> immediate offsets
    __syncthreads();            // drains prefetch(jt) — in flight a full iter

    // src: consumer V loads FIRST (before producer stage -> FIFO-safe)
    bf16x8 vf[2];
    if constexpr (CT == 1) {
#pragma unroll
      for (int kt2 = 0; kt2 < 2; ++kt2)
        vf[kt2] = *(const bf16x8*)(vb + (size_t)ln * LPOS + j0 + (2 * kt2 + h) * 8);
    }
    if (jt + 1 < iters) stage(j0 + 32, buf ^ 1);   // producer LAST
    // QK: A = K (LDS, immediate-offset reads), B = Q (pinned regs)
    f32x16 Sa, Sb;
#pragma unroll
    for (int t = 0; t < 16; ++t) { Sa[t] = 0.0f; Sb[t] = 0.0f; }
#pragma unroll
    for (int kt = 0; kt < 16; kt += 2) {
      bf16x8 ka0 = *(const bf16x8*)(ka[kt & 3] + 64 * (kt >> 2) + bo);
      Sa = __builtin_amdgcn_mfma_f32_32x32x16_bf16(ka0, qf[kt], Sa, 0, 0, 0);
      bf16x8 ka1 = *(const bf16x8*)(ka[(kt + 1) & 3] + 64 * ((kt + 1) >> 2) + bo);
      Sb = __builtin_amdgcn_mfma_f32_32x32x16_bf16(ka1, qf[kt + 1], Sb, 0, 0, 0);
    }
    // Q was pre-scaled by log2e: exp2(s_hat) == exp(s). Single v_exp_f32.
    f32x16 S;
#pragma unroll
    for (int t = 0; t < 16; ++t) S[t] = EXP2(Sa[t] + Sb[t]);

    // P^T C-layout -> PV B-frags. STATIC packs, u32 cndmask selects, xor-32.
    bf16x8 pb[2];
#pragma unroll
    for (int kh = 0; kh < 2; ++kh) {
      unsigned c0 = packbf(S[kh * 8 + 0], S[kh * 8 + 1]);
      unsigned c1 = packbf(S[kh * 8 + 2], S[kh * 8 + 3]);
      unsigned c2 = packbf(S[kh * 8 + 4], S[kh * 8 + 5]);
      unsigned c3 = packbf(S[kh * 8 + 6], S[kh * 8 + 7]);
      unsigned keep0 = h ? c2 : c0, keep1 = h ? c3 : c1;
      unsigned send0 = h ? c0 : c2, send1 = h ? c1 : c3;
      unsigned recv0 = (unsigned)__shfl_xor((int)send0, 32, 64);
      unsigned recv1 = (unsigned)__shfl_xor((int)send1, 32, 64);
      union { unsigned u[4]; bf16x8 v; } tmp;
      tmp.u[0] = h ? recv0 : keep0;
      tmp.u[1] = h ? recv1 : keep1;
      tmp.u[2] = h ? keep0 : recv0;
      tmp.u[3] = h ? keep1 : recv1;
      pb[kh] = tmp.v;
    }

    // PV: A = V (ref: LDS immediate-offset; src: regs), B = P
#pragma unroll
    for (int ct = 0; ct < CT; ++ct)
#pragma unroll
      for (int kt2 = 0; kt2 < 2; ++kt2) {
        bf16x8 vax;
        if constexpr (CT == 5)
          vax = *(const bf16x8*)(va + kt2 * 2560 + ct * 256 + bo);
        else
          vax = vf[kt2];
        O[ct] = __builtin_amdgcn_mfma_f32_32x32x16_bf16(vax, pb[kt2], O[ct], 0, 0, 0);
      }
  };

  stage(j_base, 0);
  for (int jt = 0; jt < iters; jt += 2) {   // iters is even (8 or 16)
    iter_body(jt, 0);
    iter_body(jt + 1, 1);
  }

  // epilogue: D rows = c, cols = i
#pragma unroll
  for (int ct = 0; ct < CT; ++ct)
#pragma unroll
    for (int t = 0; t < 16; ++t) {
      int c = ct * 32 + (t & 3) + 8 * (t >> 2) + 4 * h;
      dst[(size_t)c * LPOS + i_wave + ln] = O[ct][t];
    }
}

// 52 KB LDS, (256,2): full 256-reg budget (R2/R6 proved any tighter cap
// spills qf/O through scratch at a 2x cost). 2 blocks/CU.
__global__ __launch_bounds__(256, 2) void flash(
    const u16* __restrict__ qn, const u16* __restrict__ ksn, const u16* __restrict__ krn,
    const u16* __restrict__ vs, const u16* __restrict__ vr,
    float* __restrict__ nsrc, float* __restrict__ nref,
    int nch_src, int nch_ref) {
  __shared__ u16 lds[2][LDSBUF];   // 52 KB
  int tid = threadIdx.x;
  int wave = tid >> 6, lane = tid & 63;
  int idx = blockIdx.x;
  int third = idx / 3, m = idx - third * 3;
  if (m == 0) {                      // ref block
    int r = third;
    int chunk = r >> 6, b = (r >> 5) & 1, wgi = r & 31;
    int jchunk = LPOS / nch_ref;
    flash_body<5>(qn + (size_t)b * LPOS * CDIM, krn + (size_t)b * LPOS * CDIM,
                  vr + (size_t)b * 160 * LPOS,
                  nref + (size_t)(chunk * 2 + b) * 160 * LPOS,
                  lds, wave, lane, wgi * 128 + wave * 32, chunk * jchunk,
                  jchunk / 32);
  } else {                           // src block
    int r = idx - third - 1;
    int chunk = r >> 6, b = (r >> 5) & 1, wgi = r & 31;
    int jchunk = LPOS / nch_src;
    flash_body<1>(qn + (size_t)b * LPOS * CDIM, ksn + (size_t)b * LPOS * CDIM,
                  vs + (size_t)b * 32 * LPOS,
                  nsrc + (size_t)(chunk * 2 + b) * 32 * LPOS,
                  lds, wave, lane, wgi * 128 + wave * 32, chunk * jchunk,
                  jchunk / 32);
  }
}

// ---------------- finalize: sum chunks, divide by ones-channel --------------
__global__ void finalize(const float* __restrict__ nsrc, const float* __restrict__ nref,
                         float* __restrict__ out, int nch_src, int nch_ref) {
  int t = blockIdx.x * 256 + threadIdx.x;
  if (t >= 1302528) return;
  if (t < 32768) {                        // warped_src_feat [2][4][4096]
    int b = t >> 14, c = (t >> 12) & 3, i = t & 4095;
    float num = 0.f, den = 0.f;
    for (int k = 0; k < nch_src; ++k) {
      const float* base = nsrc + ((size_t)(k * 2 + b) * 32) * LPOS;
      num += base[(size_t)c * LPOS + i];
      den += base[(size_t)4 * LPOS + i];
    }
    out[t] = num / den;
  } else if (t < 65536) {                 // warped_ref_feat [2][4][4096]
    int t1 = t - 32768;
    int b = t1 >> 14, c = (t1 >> 12) & 3, i = t1 & 4095;
    float num = 0.f, den = 0.f;
    for (int k = 0; k < nch_ref; ++k) {
      const float* base = nref + ((size_t)(k * 2 + b) * 160) * LPOS;
      num += base[(size_t)(151 + c) * LPOS + i];
      den += base[(size_t)155 * LPOS + i];
    }
    out[t] = num / den;
  } else {                                // warped_ref_seg [2][151][4096]
    int t2 = t - 65536;
    int b = t2 / 618496;
    int rr = t2 % 618496;
    int c = rr >> 12, i = rr & 4095;
    float num = 0.f, den = 0.f;
    for (int k = 0; k < nch_ref; ++k) {
      const float* base = nref + ((size_t)(k * 2 + b) * 160) * LPOS;
      num += base[(size_t)c * LPOS + i];
      den += base[(size_t)155 * LPOS + i];
    }
    out[t] = num / den;
  }
}

extern "C" void kernel_launch(void* const* d_in, const int* in_sizes, int n_in,
                              void* d_out, int out_size, void* d_ws, size_t ws_size,
                              hipStream_t stream) {
  const float* trg  = (const float*)d_in[0];
  const float* srcp = (const float*)d_in[1];
  const float* refp = (const float*)d_in[2];
  const float* sfeat = (const float*)d_in[3];
  const float* rfeat = (const float*)d_in[4];
  const float* rsem  = (const float*)d_in[5];
  float* out = (float*)d_out;

  char* ws = (char*)d_ws;
  size_t o = 0;
  auto alloc = [&](size_t bytes) -> char* {
    char* p = ws + o;
    o += (bytes + 255) & ~(size_t)255;
    return p;
  };
  u16* qn  = (u16*)alloc(2ull * LPOS * CDIM * 2);
  u16* ksn = (u16*)alloc(2ull * LPOS * CDIM * 2);
  u16* krn = (u16*)alloc(2ull * LPOS * CDIM * 2);
  u16* vs  = (u16*)alloc(2ull * 32 * LPOS * 2);
  u16* vr  = (u16*)alloc(2ull * 160 * LPOS * 2);

  size_t fixed = o;
  int nch_ref = 8;                       // nch_src = 2*nch_ref (keeps 1:2 grid)
  for (;;) {
    size_t need = fixed + 512 +
                  (size_t)(2 * nch_ref) * 2 * 32 * LPOS * 4 +
                  (size_t)nch_ref * 2 * 160 * LPOS * 4;
    if (need <= ws_size || nch_ref == 1) break;
    nch_ref >>= 1;
  }
  int nch_src = 2 * nch_ref;
  float* nsrc = (float*)alloc((size_t)nch_src * 2 * 32 * LPOS * 4);
  float* nref = (float*)alloc((size_t)nch_ref * 2 * 160 * LPOS * 4);

  hipLaunchKernelGGL(norm_fused, dim3(768), dim3(256), 0, stream,
                     trg, srcp, refp, qn, ksn, krn);
  hipLaunchKernelGGL(build_v, dim3(6144), dim3(256), 0, stream,
                     sfeat, rfeat, rsem, vs, vr);
  hipLaunchKernelGGL(flash, dim3(64 * nch_ref * 3), dim3(256), 0, stream,
                     qn, ksn, krn, vs, vr, nsrc, nref, nch_src, nch_ref);
  hipLaunchKernelGGL(finalize, dim3(5088), dim3(256), 0, stream,
                     nsrc, nref, out, nch_src, nch_ref);
}